// Round 10
// baseline (424.566 us; speedup 1.0000x reference)
//
#include <hip/hip_runtime.h>
#include <math.h>

#define NN   65536      // total nodes
#define NPG  4096       // nodes per graph
#define NB   16         // graphs
#define NE   524288     // real edges
#define EPG  32768      // edges per graph
#define NH   128        // hidden
#define FN   8          // node feat
#define FE   4          // edge feat
#define NG   16         // global feat
#define NA   10         // actions
#define CAP  32         // ELL rows (max degree ~22 for Binomial(32768,1/4096) over 65k nodes)

// ---------------- fused prep: ELL fill (blocks < NE/256) + lin1 (rest) ----------------
// ELLPACK: csr[p*NN + node] — transposed so consecutive nodes' slot-p entries share
// cache lines (r9's node-major buckets put each node 256B apart -> 8x the index-load
// lines in gat). cnt IS the degree histogram (atomic cursor), no scan needed.
__global__ void prep_kernel(const int* __restrict__ ei, int* __restrict__ cnt,
                            int2* __restrict__ csr,
                            const float* __restrict__ x,
                            const float* __restrict__ Wl, const float* __restrict__ Wr,
                            float* __restrict__ xl, float* __restrict__ xr) {
    int bid = blockIdx.x;
    if (bid < NE / 256) {
        int e = bid * 256 + threadIdx.x;
        int dst = ei[NE + e];
        int pos = atomicAdd(&cnt[dst], 1);
        if (pos < CAP) csr[(size_t)pos * NN + dst] = make_int2(ei[e], e);
    } else {
        __shared__ float row[2][FN];
        int b2 = bid - NE / 256;
        int sub = threadIdx.x >> 7;
        int k = threadIdx.x & 127;
        int n = b2 * 2 + sub;
        if (k < FN) row[sub][k] = x[n * FN + k];
        __syncthreads();
        float al = 0.f, ar = 0.f;
#pragma unroll
        for (int j = 0; j < FN; ++j) {
            float v = row[sub][j];
            al += v * Wl[j * NH + k];
            ar += v * Wr[j * NH + k];
        }
        xl[n * NH + k] = al;
        xr[n * NH + k] = ar;
    }
}

// ---------------- GATv2 gather: one 32-lane group per node (r5 loop + ELL) ----------------
// Depth-2 index prefetch + depth-1 data prefetch splits the serial idx->data load
// chain across iterations. ELL index loads: one 64B line per block per edge-step.
// No running-max (scores bounded ~|6|; absmax 0.0 in r4-r9). att pre-scaled by
// log2e -> exp2f. XCD-affine swizzle keeps each graph's xl slice in one XCD L2.
// MODE 1: relu epilogue, accumulate easum, write lattr.
// MODE 2: read lattr, emit fused mean-pool partials.
template <int MODE>
__global__ __launch_bounds__(256) void gat_gather_kernel(
        const float4* __restrict__ xl, const float4* __restrict__ xr,
        const float4* __restrict__ ea,
        const int2* __restrict__ csr, const int* __restrict__ cnt,
        const float* __restrict__ We, const float* __restrict__ att,
        const float* __restrict__ bias, float* __restrict__ out,
        float4* __restrict__ lattr, float4* __restrict__ gpart) {
    __shared__ float4 red[8][32];
    int grp = threadIdx.x >> 5;
    int lane = threadIdx.x & 31;
    int bid = blockIdx.x;
    int xcd = bid & 7, slot = bid >> 3;
    int g = xcd + ((slot >> 9) << 3);   // graphs {xcd, xcd+8}
    int blk = slot & 511;               // 512 blocks x 8 nodes per graph
    int node = g * NPG + blk * 8 + grp;

    int deg = cnt[node];
    deg = deg < CAP ? deg : CAP;
    const int2* ell = csr + node;       // stride NN entries per edge-slot

    float4 xr4 = xr[node * 32 + lane];
    float4 att4 = ((const float4*)att)[lane];
    const float LOG2E = 1.44269504f;
    att4.x *= LOG2E; att4.y *= LOG2E; att4.z *= LOG2E; att4.w *= LOG2E;
    const float4* We4 = (const float4*)We;
    float4 we0 = We4[lane];
    float4 we1 = We4[32 + lane];
    float4 we2 = We4[64 + lane];
    float4 we3 = We4[96 + lane];

    float l = 0.f;
    float4 acc = make_float4(0.f, 0.f, 0.f, 0.f);
    float4 easum = make_float4(0.f, 0.f, 0.f, 0.f);

    if (deg > 0) {
        int last = deg - 1;
        int2 se0 = ell[0];
        int p1 = (1 <= last) ? 1 : last;
        int2 se1 = ell[(size_t)p1 * NN];
        float4 xl0 = xl[se0.x * 32 + lane];
        float4 a0 = ea[se0.y];
        for (int p = 0; p < deg; ++p) {
            int p2 = (p + 2 <= last) ? p + 2 : last;
            int2 se2 = ell[(size_t)p2 * NN];          // index prefetch, depth 2
            float4 xl1 = xl[se1.x * 32 + lane];       // data prefetch, depth 1
            float4 a1 = ea[se1.y];
            if (MODE == 1) {
                easum.x += a0.x; easum.y += a0.y; easum.z += a0.z; easum.w += a0.w;
            }
            float tx = xl0.x + xr4.x + a0.x * we0.x + a0.y * we1.x + a0.z * we2.x + a0.w * we3.x;
            float ty = xl0.y + xr4.y + a0.x * we0.y + a0.y * we1.y + a0.z * we2.y + a0.w * we3.y;
            float tz = xl0.z + xr4.z + a0.x * we0.z + a0.y * we1.z + a0.z * we2.z + a0.w * we3.z;
            float tw = xl0.w + xr4.w + a0.x * we0.w + a0.y * we1.w + a0.z * we2.w + a0.w * we3.w;
            tx = fmaxf(tx, 0.2f * tx);
            ty = fmaxf(ty, 0.2f * ty);
            tz = fmaxf(tz, 0.2f * tz);
            tw = fmaxf(tw, 0.2f * tw);
            float s = tx * att4.x + ty * att4.y + tz * att4.z + tw * att4.w;
#pragma unroll
            for (int o = 16; o >= 1; o >>= 1) s += __shfl_xor(s, o);   // stays in 32-group
            float w = exp2f(s);
            l += w;
            acc.x += w * xl0.x;
            acc.y += w * xl0.y;
            acc.z += w * xl0.z;
            acc.w += w * xl0.w;
            se1 = se2; xl0 = xl1; a0 = a1;
        }
    }
    // self-loop: src = node, attr = mean incoming ea
    {
        float ax, ay, az, aw;
        if (MODE == 2) {
            float4 la = lattr[node];
            ax = la.x; ay = la.y; az = la.z; aw = la.w;
        } else {
            float invd = 1.0f / (float)(deg > 0 ? deg : 1);
            ax = easum.x * invd; ay = easum.y * invd;
            az = easum.z * invd; aw = easum.w * invd;
            if (lane == 0) lattr[node] = make_float4(ax, ay, az, aw);
        }
        float4 xl4 = xl[node * 32 + lane];
        float tx = xl4.x + xr4.x + ax * we0.x + ay * we1.x + az * we2.x + aw * we3.x;
        float ty = xl4.y + xr4.y + ax * we0.y + ay * we1.y + az * we2.y + aw * we3.y;
        float tz = xl4.z + xr4.z + ax * we0.z + ay * we1.z + az * we2.z + aw * we3.z;
        float tw = xl4.w + xr4.w + ax * we0.w + ay * we1.w + az * we2.w + aw * we3.w;
        tx = fmaxf(tx, 0.2f * tx);
        ty = fmaxf(ty, 0.2f * ty);
        tz = fmaxf(tz, 0.2f * tz);
        tw = fmaxf(tw, 0.2f * tw);
        float s = tx * att4.x + ty * att4.y + tz * att4.z + tw * att4.w;
#pragma unroll
        for (int o = 16; o >= 1; o >>= 1) s += __shfl_xor(s, o);
        float w = exp2f(s);
        l += w;
        acc.x += w * xl4.x;
        acc.y += w * xl4.y;
        acc.z += w * xl4.z;
        acc.w += w * xl4.w;
    }
    float inv = 1.0f / l;
    float4 b4 = ((const float4*)bias)[lane];
    float4 o4;
    o4.x = acc.x * inv + b4.x;
    o4.y = acc.y * inv + b4.y;
    o4.z = acc.z * inv + b4.z;
    o4.w = acc.w * inv + b4.w;
    if (MODE == 1) {
        o4.x = fmaxf(o4.x, 0.f); o4.y = fmaxf(o4.y, 0.f);
        o4.z = fmaxf(o4.z, 0.f); o4.w = fmaxf(o4.w, 0.f);
    }
    ((float4*)out)[node * 32 + lane] = o4;

    // fused mean-pool partials: sum o4 over the 8 node-groups of this block
    if (MODE == 2) {
        red[grp][lane] = o4;
        __syncthreads();
        if (grp < 4) {
            float4 o = red[grp + 4][lane];
            red[grp][lane] = make_float4(red[grp][lane].x + o.x, red[grp][lane].y + o.y,
                                         red[grp][lane].z + o.z, red[grp][lane].w + o.w);
        }
        __syncthreads();
        if (grp < 2) {
            float4 o = red[grp + 2][lane];
            red[grp][lane] = make_float4(red[grp][lane].x + o.x, red[grp][lane].y + o.y,
                                         red[grp][lane].z + o.z, red[grp][lane].w + o.w);
        }
        __syncthreads();
        if (grp == 0) {
            float4 a = red[0][lane], b = red[1][lane];
            gpart[(g * 512 + blk) * 32 + lane] =
                make_float4(a.x + b.x, a.y + b.y, a.z + b.z, a.w + b.w);
        }
    }
}

// ---------------- layer-2 projections: 64x64 tile, BOTH matrices per block ----------------
#define FMA4(accv, s, bv) do { accv.x += (s) * (bv).x; accv.y += (s) * (bv).y; \
                               accv.z += (s) * (bv).z; accv.w += (s) * (bv).w; } while (0)
__global__ __launch_bounds__(256) void lin2_gemm_kernel(
        const float* __restrict__ A, const float* __restrict__ Wl2,
        const float* __restrict__ Wr2, float* __restrict__ xl, float* __restrict__ xr) {
    __shared__ __align__(16) float As[64][20];
    __shared__ __align__(16) float Bl[16][64];
    __shared__ __align__(16) float Br[16][64];
    int rowBase = blockIdx.x * 64;
    int colBase = blockIdx.y * 64;
    int t = threadIdx.x;
    int tx = t & 15, ty = t >> 4;
    int ar = t >> 2, aq = (t & 3) * 4;
    int brow = t >> 4, bcol = (t & 15) * 4;
    float4 accL[4] = {};
    float4 accR[4] = {};
    for (int kk = 0; kk < NH; kk += 16) {
        float4 av = *(const float4*)&A[(size_t)(rowBase + ar) * NH + kk + aq];
        float4 blv = *(const float4*)&Wl2[(size_t)(kk + brow) * NH + colBase + bcol];
        float4 brv = *(const float4*)&Wr2[(size_t)(kk + brow) * NH + colBase + bcol];
        __syncthreads();
        *(float4*)&As[ar][aq] = av;
        *(float4*)&Bl[brow][bcol] = blv;
        *(float4*)&Br[brow][bcol] = brv;
        __syncthreads();
#pragma unroll
        for (int c4 = 0; c4 < 4; ++c4) {
            float4 a4[4], bl4[4], br4[4];
#pragma unroll
            for (int i = 0; i < 4; ++i) a4[i] = *(const float4*)&As[ty * 4 + i][c4 * 4];
#pragma unroll
            for (int j = 0; j < 4; ++j) {
                bl4[j] = *(const float4*)&Bl[c4 * 4 + j][tx * 4];
                br4[j] = *(const float4*)&Br[c4 * 4 + j][tx * 4];
            }
#pragma unroll
            for (int i = 0; i < 4; ++i) {
                FMA4(accL[i], a4[i].x, bl4[0]);
                FMA4(accL[i], a4[i].y, bl4[1]);
                FMA4(accL[i], a4[i].z, bl4[2]);
                FMA4(accL[i], a4[i].w, bl4[3]);
                FMA4(accR[i], a4[i].x, br4[0]);
                FMA4(accR[i], a4[i].y, br4[1]);
                FMA4(accR[i], a4[i].z, br4[2]);
                FMA4(accR[i], a4[i].w, br4[3]);
            }
        }
    }
#pragma unroll
    for (int i = 0; i < 4; ++i) {
        size_t off = (size_t)(rowBase + ty * 4 + i) * NH + colBase + tx * 4;
        *(float4*)&xl[off] = accL[i];
        *(float4*)&xr[off] = accR[i];
    }
}

// ---------------- head MLP: one block per graph (sums fused-pool partials) ----------------
__global__ void head_kernel(const float* __restrict__ gpart, const float* __restrict__ h,
                            const float* __restrict__ gstate, const int* __restrict__ cpn,
                            const float* __restrict__ Wc, const float* __restrict__ bc,
                            const float* __restrict__ Wa1, const float* __restrict__ ba1,
                            const float* __restrict__ Wa2, const float* __restrict__ ba2,
                            const float* __restrict__ Wv1, const float* __restrict__ bv1,
                            const float* __restrict__ Wv2, const float* __restrict__ bv2,
                            float* __restrict__ out) {
    int b = blockIdx.x, t = threadIdx.x;
    __shared__ float comb[400];
    __shared__ float feat[256];
    __shared__ float hid[256];
    int n0 = cpn[b * 2 + 0] + b * NPG;
    int n1 = cpn[b * 2 + 1] + b * NPG;
    if (t < 128) {
        float s0 = 0.f, s1 = 0.f, s2 = 0.f, s3 = 0.f;
        const float* gp = gpart + (size_t)b * 512 * NH + t;
        for (int c = 0; c < 512; c += 4) {
            s0 += gp[(c + 0) * NH];
            s1 += gp[(c + 1) * NH];
            s2 += gp[(c + 2) * NH];
            s3 += gp[(c + 3) * NH];
        }
        comb[t] = (s0 + s1 + s2 + s3) * (1.0f / NPG);
        comb[128 + t] = h[n0 * NH + t];
    } else {
        int tt = t - 128;
        comb[256 + tt] = h[n1 * NH + tt];
        if (tt < NG) comb[384 + tt] = gstate[b * NG + tt];
    }
    __syncthreads();
    float acc = bc[t];
    for (int j = 0; j < 400; ++j) acc += comb[j] * Wc[j * 256 + t];
    feat[t] = fmaxf(acc, 0.f);
    __syncthreads();
    if (t < 128) {
        float a2 = ba1[t];
        for (int j = 0; j < 256; ++j) a2 += feat[j] * Wa1[j * NH + t];
        hid[t] = fmaxf(a2, 0.f);
    } else {
        int tt = t - 128;
        float a2 = bv1[tt];
        for (int j = 0; j < 256; ++j) a2 += feat[j] * Wv1[j * NH + tt];
        hid[128 + tt] = fmaxf(a2, 0.f);
    }
    __syncthreads();
    if (t < NA) {
        float a2 = ba2[t];
        for (int j = 0; j < NH; ++j) a2 += hid[j] * Wa2[j * NA + t];
        out[b * 11 + t] = a2;
    } else if (t == NA) {
        float a2 = bv2[0];
        for (int j = 0; j < NH; ++j) a2 += hid[128 + j] * Wv2[j];
        out[b * 11 + 10] = a2;
    }
}

extern "C" void kernel_launch(void* const* d_in, const int* in_sizes, int n_in,
                              void* d_out, int out_size, void* d_ws, size_t ws_size,
                              hipStream_t stream) {
    const float* x      = (const float*)d_in[0];
    const int*   ei     = (const int*)d_in[1];
    const float* ea     = (const float*)d_in[2];
    const float* gstate = (const float*)d_in[3];
    const int*   cpn    = (const int*)d_in[4];
    const float* Wl1 = (const float*)d_in[5];
    const float* Wr1 = (const float*)d_in[6];
    const float* We1 = (const float*)d_in[7];
    const float* att1= (const float*)d_in[8];
    const float* b1  = (const float*)d_in[9];
    const float* Wl2 = (const float*)d_in[10];
    const float* Wr2 = (const float*)d_in[11];
    const float* We2 = (const float*)d_in[12];
    const float* att2= (const float*)d_in[13];
    const float* b2  = (const float*)d_in[14];
    const float* Wc  = (const float*)d_in[15];
    const float* bc  = (const float*)d_in[16];
    const float* Wa1 = (const float*)d_in[17];
    const float* ba1 = (const float*)d_in[18];
    const float* Wa2 = (const float*)d_in[19];
    const float* ba2 = (const float*)d_in[20];
    const float* Wv1 = (const float*)d_in[21];
    const float* bv1 = (const float*)d_in[22];
    const float* Wv2 = (const float*)d_in[23];
    const float* bv2 = (const float*)d_in[24];

    char* ws = (char*)d_ws;
    size_t o = 0;
    float* xl    = (float*)(ws + o); o += (size_t)NN * NH * 4;   // 32 MB
    float* xr    = (float*)(ws + o); o += (size_t)NN * NH * 4;   // 32 MB
    float* h     = (float*)(ws + o); o += (size_t)NN * NH * 4;   // 32 MB
    float* lattr = (float*)(ws + o); o += (size_t)NN * 16;       // 1 MB
    float* gpart = (float*)(ws + o); o += (size_t)NB * 512 * NH * 4;  // 4 MB
    int*   cnt   = (int*)(ws + o);   o += (size_t)NN * 4;        // 256 KB
    int2*  csr   = (int2*)(ws + o);  o += (size_t)NN * CAP * 8;  // 16 MB (ELL)
    (void)o; (void)ws_size; (void)in_sizes; (void)n_in; (void)out_size;

    hipMemsetAsync(cnt, 0, (size_t)NN * 4, stream);
    prep_kernel<<<NE / 256 + NN / 2, 256, 0, stream>>>(ei, cnt, csr, x, Wl1, Wr1, xl, xr);
    gat_gather_kernel<1><<<NN / 8, 256, 0, stream>>>((const float4*)xl, (const float4*)xr,
        (const float4*)ea, csr, cnt, We1, att1, b1, h, (float4*)lattr, nullptr);
    lin2_gemm_kernel<<<dim3(NN / 64, 2), 256, 0, stream>>>(h, Wl2, Wr2, xl, xr);
    gat_gather_kernel<2><<<NN / 8, 256, 0, stream>>>((const float4*)xl, (const float4*)xr,
        (const float4*)ea, csr, cnt, We2, att2, b2, h, (float4*)lattr, (float4*)gpart);
    head_kernel<<<NB, 256, 0, stream>>>(gpart, h, gstate, cpn, Wc, bc, Wa1, ba1, Wa2, ba2,
                                        Wv1, bv1, Wv2, bv2, (float*)d_out);
}

// Round 11
// 366.088 us; speedup vs baseline: 1.1597x; 1.1597x over previous
//
#include <hip/hip_runtime.h>
#include <math.h>

#define NN   65536      // total nodes
#define NPG  4096       // nodes per graph
#define NB   16         // graphs
#define NE   524288     // real edges
#define EPG  32768      // edges per graph
#define NH   128        // hidden
#define FN   8          // node feat
#define FE   4          // edge feat
#define NG   16         // global feat
#define NA   10         // actions

// ---------------- fused: degree histogram (blocks < NE/256) + lin1 (rest) ----------------
__global__ void hist_lin1_kernel(const int* __restrict__ ei, int* __restrict__ deg,
                                 const float* __restrict__ x,
                                 const float* __restrict__ Wl, const float* __restrict__ Wr,
                                 float* __restrict__ xl, float* __restrict__ xr) {
    int bid = blockIdx.x;
    if (bid < NE / 256) {
        int e = bid * 256 + threadIdx.x;
        atomicAdd(&deg[ei[NE + e]], 1);
    } else {
        __shared__ float row[2][FN];
        int b2 = bid - NE / 256;
        int sub = threadIdx.x >> 7;
        int k = threadIdx.x & 127;
        int n = b2 * 2 + sub;
        if (k < FN) row[sub][k] = x[n * FN + k];
        __syncthreads();
        float al = 0.f, ar = 0.f;
#pragma unroll
        for (int j = 0; j < FN; ++j) {
            float v = row[sub][j];
            al += v * Wl[j * NH + k];
            ar += v * Wr[j * NH + k];
        }
        xl[n * NH + k] = al;
        xr[n * NH + k] = ar;
    }
}

// ---------------- per-graph exclusive scan of deg -> offs, cursor ----------------
__global__ __launch_bounds__(1024) void scan_kernel(
        const int* __restrict__ deg, int* __restrict__ offs, int* __restrict__ cursor) {
    __shared__ int psum[1024];
    int g = blockIdx.x, t = threadIdx.x;
    int nbase = g * NPG + t * 4;
    int d[4];
    int loc[4];
    int run = 0;
#pragma unroll
    for (int i = 0; i < 4; ++i) { d[i] = deg[nbase + i]; loc[i] = run; run += d[i]; }
    psum[t] = run;
    __syncthreads();
    for (int s = 1; s < 1024; s <<= 1) {
        int add = (t >= s) ? psum[t - s] : 0;
        __syncthreads();
        psum[t] += add;
        __syncthreads();
    }
    int prefix = (t == 0) ? 0 : psum[t - 1];
    int ebase = g * EPG;
#pragma unroll
    for (int i = 0; i < 4; ++i) {
        int v = ebase + prefix + loc[i];
        offs[nbase + i] = v;
        cursor[nbase + i] = v;
    }
    if (g == NB - 1 && t == 0) offs[NN] = NE;
}

// ---------------- CSR fill: packed (src,eid) int2, graph-contiguous ----------------
__global__ void csr_fill_kernel(const int* __restrict__ ei, int* __restrict__ cursor,
                                int2* __restrict__ csr) {
    int e = blockIdx.x * 256 + threadIdx.x;
    int dst = ei[NE + e];
    int pos = atomicAdd(&cursor[dst], 1);
    csr[pos] = make_int2(ei[e], e);
}

// ---------------- GATv2 gather: one 32-lane group per node (measured-best r6 config) ----------------
// Depth-2 index prefetch + depth-1 data prefetch. Contiguous per-graph CSR (offs).
// No running-max (scores bounded ~|6|; absmax 0.0 in r4-r10).
// XCD-affine swizzle keeps each graph's xl slice in one XCD's L2.
// Layer 1 (lattr_r==null): relu epilogue, accumulate easum, write lattr.
// Layer 2 (gpart!=null): read lattr, emit fused mean-pool partials.
__global__ __launch_bounds__(256) void gat_gather_kernel(
        const float4* __restrict__ xl, const float4* __restrict__ xr,
        const float4* __restrict__ ea,
        const int2* __restrict__ csr, const int* __restrict__ offs,
        const float* __restrict__ We, const float* __restrict__ att,
        const float* __restrict__ bias, float* __restrict__ out,
        float4* __restrict__ lattr_w, const float4* __restrict__ lattr_r,
        float4* __restrict__ gpart, int do_relu) {
    __shared__ float4 red[8][32];
    int grp = threadIdx.x >> 5;
    int lane = threadIdx.x & 31;
    int bid = blockIdx.x;
    int xcd = bid & 7, slot = bid >> 3;
    int g = xcd + ((slot >> 9) << 3);   // graphs {xcd, xcd+8}
    int blk = slot & 511;               // block within graph (512 x 8 nodes)
    int node = g * NPG + blk * 8 + grp;

    float4 xr4 = xr[node * 32 + lane];
    float4 att4 = ((const float4*)att)[lane];
    const float4* We4 = (const float4*)We;
    float4 we0 = We4[lane];
    float4 we1 = We4[32 + lane];
    float4 we2 = We4[64 + lane];
    float4 we3 = We4[96 + lane];

    int beg = offs[node], end = offs[node + 1];
    float l = 0.f;
    float4 acc = make_float4(0.f, 0.f, 0.f, 0.f);
    float4 easum = make_float4(0.f, 0.f, 0.f, 0.f);
    bool have_lattr = (lattr_r != nullptr);
    if (beg < end) {
        int last = end - 1;
        int2 se0 = csr[beg];
        int p1 = (beg + 1 <= last) ? beg + 1 : last;
        int2 se1 = csr[p1];
        float4 xl0 = xl[se0.x * 32 + lane];
        float4 a0 = ea[se0.y];
        for (int p = beg; p < end; ++p) {
            int p2 = (p + 2 <= last) ? p + 2 : last;
            int2 se2 = csr[p2];                       // index prefetch, depth 2
            float4 xl1 = xl[se1.x * 32 + lane];       // data prefetch, depth 1
            float4 a1 = ea[se1.y];
            if (!have_lattr) {
                easum.x += a0.x; easum.y += a0.y; easum.z += a0.z; easum.w += a0.w;
            }
            float tx = xl0.x + xr4.x + a0.x * we0.x + a0.y * we1.x + a0.z * we2.x + a0.w * we3.x;
            float ty = xl0.y + xr4.y + a0.x * we0.y + a0.y * we1.y + a0.z * we2.y + a0.w * we3.y;
            float tz = xl0.z + xr4.z + a0.x * we0.z + a0.y * we1.z + a0.z * we2.z + a0.w * we3.z;
            float tw = xl0.w + xr4.w + a0.x * we0.w + a0.y * we1.w + a0.z * we2.w + a0.w * we3.w;
            tx = tx > 0.f ? tx : 0.2f * tx;
            ty = ty > 0.f ? ty : 0.2f * ty;
            tz = tz > 0.f ? tz : 0.2f * tz;
            tw = tw > 0.f ? tw : 0.2f * tw;
            float s = tx * att4.x + ty * att4.y + tz * att4.z + tw * att4.w;
#pragma unroll
            for (int o = 16; o >= 1; o >>= 1) s += __shfl_xor(s, o);   // stays in 32-group
            float w = __expf(s);
            l += w;
            acc.x += w * xl0.x;
            acc.y += w * xl0.y;
            acc.z += w * xl0.z;
            acc.w += w * xl0.w;
            se1 = se2; xl0 = xl1; a0 = a1;
        }
    }
    // self-loop: src = node, attr = mean incoming ea
    {
        float ax, ay, az, aw;
        if (have_lattr) {
            float4 la = lattr_r[node];
            ax = la.x; ay = la.y; az = la.z; aw = la.w;
        } else {
            int deg = end - beg;
            float invd = 1.0f / (float)(deg > 0 ? deg : 1);
            ax = easum.x * invd; ay = easum.y * invd;
            az = easum.z * invd; aw = easum.w * invd;
            if (lane == 0) lattr_w[node] = make_float4(ax, ay, az, aw);
        }
        float4 xl4 = xl[node * 32 + lane];
        float tx = xl4.x + xr4.x + ax * we0.x + ay * we1.x + az * we2.x + aw * we3.x;
        float ty = xl4.y + xr4.y + ax * we0.y + ay * we1.y + az * we2.y + aw * we3.y;
        float tz = xl4.z + xr4.z + ax * we0.z + ay * we1.z + az * we2.z + aw * we3.z;
        float tw = xl4.w + xr4.w + ax * we0.w + ay * we1.w + az * we2.w + aw * we3.w;
        tx = tx > 0.f ? tx : 0.2f * tx;
        ty = ty > 0.f ? ty : 0.2f * ty;
        tz = tz > 0.f ? tz : 0.2f * tz;
        tw = tw > 0.f ? tw : 0.2f * tw;
        float s = tx * att4.x + ty * att4.y + tz * att4.z + tw * att4.w;
#pragma unroll
        for (int o = 16; o >= 1; o >>= 1) s += __shfl_xor(s, o);
        float w = __expf(s);
        l += w;
        acc.x += w * xl4.x;
        acc.y += w * xl4.y;
        acc.z += w * xl4.z;
        acc.w += w * xl4.w;
    }
    float inv = 1.0f / l;
    float4 b4 = ((const float4*)bias)[lane];
    float4 o4;
    o4.x = acc.x * inv + b4.x;
    o4.y = acc.y * inv + b4.y;
    o4.z = acc.z * inv + b4.z;
    o4.w = acc.w * inv + b4.w;
    if (do_relu) {
        o4.x = fmaxf(o4.x, 0.f); o4.y = fmaxf(o4.y, 0.f);
        o4.z = fmaxf(o4.z, 0.f); o4.w = fmaxf(o4.w, 0.f);
    }
    ((float4*)out)[node * 32 + lane] = o4;

    // fused mean-pool partials: sum o4 over the 8 node-groups of this block
    if (gpart != nullptr) {
        red[grp][lane] = o4;
        __syncthreads();
        if (grp < 4) {
            float4 o = red[grp + 4][lane];
            red[grp][lane] = make_float4(red[grp][lane].x + o.x, red[grp][lane].y + o.y,
                                         red[grp][lane].z + o.z, red[grp][lane].w + o.w);
        }
        __syncthreads();
        if (grp < 2) {
            float4 o = red[grp + 2][lane];
            red[grp][lane] = make_float4(red[grp][lane].x + o.x, red[grp][lane].y + o.y,
                                         red[grp][lane].z + o.z, red[grp][lane].w + o.w);
        }
        __syncthreads();
        if (grp == 0) {
            float4 a = red[0][lane], b = red[1][lane];
            gpart[(g * 512 + blk) * 32 + lane] =
                make_float4(a.x + b.x, a.y + b.y, a.z + b.z, a.w + b.w);
        }
    }
}

// ---------------- layer-2 projections: 64x64 tile, BOTH matrices per block ----------------
#define FMA4(accv, s, bv) do { accv.x += (s) * (bv).x; accv.y += (s) * (bv).y; \
                               accv.z += (s) * (bv).z; accv.w += (s) * (bv).w; } while (0)
__global__ __launch_bounds__(256) void lin2_gemm_kernel(
        const float* __restrict__ A, const float* __restrict__ Wl2,
        const float* __restrict__ Wr2, float* __restrict__ xl, float* __restrict__ xr) {
    __shared__ __align__(16) float As[64][20];
    __shared__ __align__(16) float Bl[16][64];
    __shared__ __align__(16) float Br[16][64];
    int rowBase = blockIdx.x * 64;
    int colBase = blockIdx.y * 64;
    int t = threadIdx.x;
    int tx = t & 15, ty = t >> 4;
    int ar = t >> 2, aq = (t & 3) * 4;
    int brow = t >> 4, bcol = (t & 15) * 4;
    float4 accL[4] = {};
    float4 accR[4] = {};
    for (int kk = 0; kk < NH; kk += 16) {
        float4 av = *(const float4*)&A[(size_t)(rowBase + ar) * NH + kk + aq];
        float4 blv = *(const float4*)&Wl2[(size_t)(kk + brow) * NH + colBase + bcol];
        float4 brv = *(const float4*)&Wr2[(size_t)(kk + brow) * NH + colBase + bcol];
        __syncthreads();
        *(float4*)&As[ar][aq] = av;
        *(float4*)&Bl[brow][bcol] = blv;
        *(float4*)&Br[brow][bcol] = brv;
        __syncthreads();
#pragma unroll
        for (int c4 = 0; c4 < 4; ++c4) {
            float4 a4[4], bl4[4], br4[4];
#pragma unroll
            for (int i = 0; i < 4; ++i) a4[i] = *(const float4*)&As[ty * 4 + i][c4 * 4];
#pragma unroll
            for (int j = 0; j < 4; ++j) {
                bl4[j] = *(const float4*)&Bl[c4 * 4 + j][tx * 4];
                br4[j] = *(const float4*)&Br[c4 * 4 + j][tx * 4];
            }
#pragma unroll
            for (int i = 0; i < 4; ++i) {
                FMA4(accL[i], a4[i].x, bl4[0]);
                FMA4(accL[i], a4[i].y, bl4[1]);
                FMA4(accL[i], a4[i].z, bl4[2]);
                FMA4(accL[i], a4[i].w, bl4[3]);
                FMA4(accR[i], a4[i].x, br4[0]);
                FMA4(accR[i], a4[i].y, br4[1]);
                FMA4(accR[i], a4[i].z, br4[2]);
                FMA4(accR[i], a4[i].w, br4[3]);
            }
        }
    }
#pragma unroll
    for (int i = 0; i < 4; ++i) {
        size_t off = (size_t)(rowBase + ty * 4 + i) * NH + colBase + tx * 4;
        *(float4*)&xl[off] = accL[i];
        *(float4*)&xr[off] = accR[i];
    }
}

// ---------------- head MLP: one block per graph (sums fused-pool partials) ----------------
__global__ void head_kernel(const float* __restrict__ gpart, const float* __restrict__ h,
                            const float* __restrict__ gstate, const int* __restrict__ cpn,
                            const float* __restrict__ Wc, const float* __restrict__ bc,
                            const float* __restrict__ Wa1, const float* __restrict__ ba1,
                            const float* __restrict__ Wa2, const float* __restrict__ ba2,
                            const float* __restrict__ Wv1, const float* __restrict__ bv1,
                            const float* __restrict__ Wv2, const float* __restrict__ bv2,
                            float* __restrict__ out) {
    int b = blockIdx.x, t = threadIdx.x;
    __shared__ float comb[400];
    __shared__ float feat[256];
    __shared__ float hid[256];
    int n0 = cpn[b * 2 + 0] + b * NPG;
    int n1 = cpn[b * 2 + 1] + b * NPG;
    if (t < 128) {
        float s0 = 0.f, s1 = 0.f, s2 = 0.f, s3 = 0.f;
        const float* gp = gpart + (size_t)b * 512 * NH + t;
        for (int c = 0; c < 512; c += 4) {
            s0 += gp[(c + 0) * NH];
            s1 += gp[(c + 1) * NH];
            s2 += gp[(c + 2) * NH];
            s3 += gp[(c + 3) * NH];
        }
        comb[t] = (s0 + s1 + s2 + s3) * (1.0f / NPG);
        comb[128 + t] = h[n0 * NH + t];
    } else {
        int tt = t - 128;
        comb[256 + tt] = h[n1 * NH + tt];
        if (tt < NG) comb[384 + tt] = gstate[b * NG + tt];
    }
    __syncthreads();
    float acc = bc[t];
    for (int j = 0; j < 400; ++j) acc += comb[j] * Wc[j * 256 + t];
    feat[t] = fmaxf(acc, 0.f);
    __syncthreads();
    if (t < 128) {
        float a2 = ba1[t];
        for (int j = 0; j < 256; ++j) a2 += feat[j] * Wa1[j * NH + t];
        hid[t] = fmaxf(a2, 0.f);
    } else {
        int tt = t - 128;
        float a2 = bv1[tt];
        for (int j = 0; j < 256; ++j) a2 += feat[j] * Wv1[j * NH + tt];
        hid[128 + tt] = fmaxf(a2, 0.f);
    }
    __syncthreads();
    if (t < NA) {
        float a2 = ba2[t];
        for (int j = 0; j < NH; ++j) a2 += hid[j] * Wa2[j * NA + t];
        out[b * 11 + t] = a2;
    } else if (t == NA) {
        float a2 = bv2[0];
        for (int j = 0; j < NH; ++j) a2 += hid[128 + j] * Wv2[j];
        out[b * 11 + 10] = a2;
    }
}

extern "C" void kernel_launch(void* const* d_in, const int* in_sizes, int n_in,
                              void* d_out, int out_size, void* d_ws, size_t ws_size,
                              hipStream_t stream) {
    const float* x      = (const float*)d_in[0];
    const int*   ei     = (const int*)d_in[1];
    const float* ea     = (const float*)d_in[2];
    const float* gstate = (const float*)d_in[3];
    const int*   cpn    = (const int*)d_in[4];
    const float* Wl1 = (const float*)d_in[5];
    const float* Wr1 = (const float*)d_in[6];
    const float* We1 = (const float*)d_in[7];
    const float* att1= (const float*)d_in[8];
    const float* b1  = (const float*)d_in[9];
    const float* Wl2 = (const float*)d_in[10];
    const float* Wr2 = (const float*)d_in[11];
    const float* We2 = (const float*)d_in[12];
    const float* att2= (const float*)d_in[13];
    const float* b2  = (const float*)d_in[14];
    const float* Wc  = (const float*)d_in[15];
    const float* bc  = (const float*)d_in[16];
    const float* Wa1 = (const float*)d_in[17];
    const float* ba1 = (const float*)d_in[18];
    const float* Wa2 = (const float*)d_in[19];
    const float* ba2 = (const float*)d_in[20];
    const float* Wv1 = (const float*)d_in[21];
    const float* bv1 = (const float*)d_in[22];
    const float* Wv2 = (const float*)d_in[23];
    const float* bv2 = (const float*)d_in[24];

    char* ws = (char*)d_ws;
    size_t o = 0;
    float* xl    = (float*)(ws + o); o += (size_t)NN * NH * 4;   // 32 MB
    float* xr    = (float*)(ws + o); o += (size_t)NN * NH * 4;   // 32 MB
    float* h     = (float*)(ws + o); o += (size_t)NN * NH * 4;   // 32 MB
    float* lattr = (float*)(ws + o); o += (size_t)NN * 16;       // 1 MB
    float* gpart = (float*)(ws + o); o += (size_t)NB * 512 * NH * 4;  // 4 MB
    int*   offs  = (int*)(ws + o);   o += (((size_t)(NN + 1) * 4 + 255) & ~(size_t)255);
    int*   cursor= (int*)(ws + o);   o += (size_t)NN * 4;
    int*   deg   = (int*)(ws + o);   o += (size_t)NN * 4;
    int2*  csr   = (int2*)(ws + o);  o += (size_t)NE * 8;        // 4 MB
    (void)o; (void)ws_size; (void)in_sizes; (void)n_in; (void)out_size;

    hipMemsetAsync(deg, 0, (size_t)NN * 4, stream);
    hist_lin1_kernel<<<NE / 256 + NN / 2, 256, 0, stream>>>(ei, deg, x, Wl1, Wr1, xl, xr);
    scan_kernel<<<NB, 1024, 0, stream>>>(deg, offs, cursor);
    csr_fill_kernel<<<NE / 256, 256, 0, stream>>>(ei, cursor, csr);
    gat_gather_kernel<<<NN / 8, 256, 0, stream>>>((const float4*)xl, (const float4*)xr,
        (const float4*)ea, csr, offs, We1, att1, b1, h, (float4*)lattr, nullptr, nullptr, 1);
    lin2_gemm_kernel<<<dim3(NN / 64, 2), 256, 0, stream>>>(h, Wl2, Wr2, xl, xr);
    gat_gather_kernel<<<NN / 8, 256, 0, stream>>>((const float4*)xl, (const float4*)xr,
        (const float4*)ea, csr, offs, We2, att2, b2, h, nullptr, (const float4*)lattr,
        (float4*)gpart, 0);
    head_kernel<<<NB, 256, 0, stream>>>(gpart, h, gstate, cpn, Wc, bc, Wa1, ba1, Wa2, ba2,
                                        Wv1, bv1, Wv2, bv2, (float*)d_out);
}